// Round 7
// baseline (1539.045 us; speedup 1.0000x reference)
//
#include <hip/hip_runtime.h>

// Problem dims
#define BATCH 256
#define TLEN  512
#define DIN   128
#define DFEAT 256
#define DLAT  512
#define G4    2048   // 4*DLAT
#define KCAT  768    // DFEAT + DLAT

typedef __bf16 bf16x8 __attribute__((ext_vector_type(8)));
typedef float f32x4 __attribute__((ext_vector_type(4)));

typedef __attribute__((address_space(1))) const unsigned int glb_u32;
typedef __attribute__((address_space(3))) unsigned int lds_u32;

// ws layout (bytes)
#define WCAT_OFF   0u          // 768x2048 bf16 frag-linear: 3,145,728
#define WENC_OFF   3145728u    // 128x256  bf16 frag-linear: 65,536
#define ENC_OFF    3211264u    // enc bf16 [T][B][256]: 67,108,864
#define H_OFF      70320128u   // h dbuf bf16 [2][256][512]: 524,288
#define FLAG_OFF   70844416u   // flags: (grp*16+widx)*16 + wave, 16,384 B

__device__ __forceinline__ float sigf(float x)  { return 1.0f / (1.0f + __expf(-x)); }
__device__ __forceinline__ float tanhfast(float x){ return 2.0f / (1.0f + __expf(-2.0f * x)) - 1.0f; }
__device__ __forceinline__ unsigned short bfb(float f) {
    __bf16 b = (__bf16)f;
    return __builtin_bit_cast(unsigned short, b);
}

// ---------------------------------------------------------------------------
// Weight prep: bf16 fragment-linear copies of [W_x;W_h] (768x2048) and W_enc.
// wcat chunk cid = (((widx*8 + np*2 + nt2)*24 + ks)*64 + l) holds
// B[k = ks*32+(l>>4)*8 .. +8][col], col = np*512 + widx*32 + nt2*16 + (l&15).
// ---------------------------------------------------------------------------
__global__ __launch_bounds__(256) void wprep_kernel(const float* __restrict__ Wx,
                                                    const float* __restrict__ Wh,
                                                    const float* __restrict__ Wenc,
                                                    __bf16* __restrict__ wcat,
                                                    __bf16* __restrict__ wencf) {
    int cid = blockIdx.x * 256 + threadIdx.x;   // 200704 total
    float v[8];
    __bf16* dst;
    if (cid < 196608) {
        int widx = cid / 12288;      // 16 wgs
        int r1 = cid % 12288;
        int nn = r1 / 1536;          // np*2 + nt2, 0..7
        int r2 = r1 % 1536;
        int ks = r2 >> 6, l = r2 & 63;
        int col = (nn >> 1) * 512 + widx * 32 + (nn & 1) * 16 + (l & 15);
        int kc = ks * 32 + (l >> 4) * 8;
#pragma unroll
        for (int j = 0; j < 8; ++j) {
            int kk = kc + j;
            v[j] = (kk < DFEAT) ? Wx[kk * G4 + col] : Wh[(kk - DFEAT) * G4 + col];
        }
        dst = wcat + (size_t)cid * 8;
    } else {
        int c2 = cid - 196608;   // [0, 4096)
        int ntg = c2 >> 8;
        int r = c2 & 255;
        int ks = r >> 6, l = r & 63;
        int col = ntg * 16 + (l & 15);
        int kc = ks * 32 + (l >> 4) * 8;
#pragma unroll
        for (int j = 0; j < 8; ++j) v[j] = Wenc[(kc + j) * DFEAT + col];
        dst = wencf + (size_t)c2 * 8;
    }
    bf16x8 o;
#pragma unroll
    for (int j = 0; j < 8; ++j) o[j] = (__bf16)v[j];
    *reinterpret_cast<bf16x8*>(dst) = o;
}

// ---------------------------------------------------------------------------
// Encoder: enc[t][b][f] = tanh(x[b][t][:] @ W_enc + b_enc), bf16 out.
// ---------------------------------------------------------------------------
__global__ __launch_bounds__(256) void enc_kernel(const float* __restrict__ x,
                                                  const float* __restrict__ benc,
                                                  const __bf16* __restrict__ wencf,
                                                  __bf16* __restrict__ enc) {
    __shared__ uint4 afrag4[1024];   // 16 KB frag-linear A
    __bf16* afrag = reinterpret_cast<__bf16*>(afrag4);
    int tid = threadIdx.x;
    int lane = tid & 63, w = tid >> 6;
    int rid0 = blockIdx.x * 64;
    int ntg0 = blockIdx.y * 4;

    bf16x8 wr[4][4];
#pragma unroll
    for (int n = 0; n < 4; ++n)
#pragma unroll
        for (int ks = 0; ks < 4; ++ks)
            wr[n][ks] = *reinterpret_cast<const bf16x8*>(
                wencf + (size_t)(((ntg0 + n) * 4 + ks) * 64 + lane) * 8);
    float bias[4];
#pragma unroll
    for (int n = 0; n < 4; ++n) bias[n] = benc[(ntg0 + n) * 16 + (lane & 15)];

#pragma unroll
    for (int i = 0; i < 4; ++i) {
        int c = tid + 256 * i;          // [0,1024): row = c>>4, k8 = c&15
        int row = c >> 4, k8 = c & 15;
        const float* src = x + (size_t)(rid0 + row) * DIN + k8 * 8;
        float4 f0 = *reinterpret_cast<const float4*>(src);
        float4 f1 = *reinterpret_cast<const float4*>(src + 4);
        bf16x8 o;
        o[0] = (__bf16)f0.x; o[1] = (__bf16)f0.y; o[2] = (__bf16)f0.z; o[3] = (__bf16)f0.w;
        o[4] = (__bf16)f1.x; o[5] = (__bf16)f1.y; o[6] = (__bf16)f1.z; o[7] = (__bf16)f1.w;
        int l = (k8 & 3) * 16 + (row & 15);
        int a16 = ((row >> 4) * 4 + (k8 >> 2)) * 64 + l;
        *reinterpret_cast<bf16x8*>(afrag + (size_t)a16 * 8) = o;
    }
    __syncthreads();

    int m = w;
    f32x4 acc[4];
#pragma unroll
    for (int n = 0; n < 4; ++n) acc[n] = (f32x4){bias[n], bias[n], bias[n], bias[n]};
#pragma unroll
    for (int ks = 0; ks < 4; ++ks) {
        bf16x8 a = *reinterpret_cast<const bf16x8*>(afrag + (size_t)((m * 4 + ks) * 64 + lane) * 8);
#pragma unroll
        for (int n = 0; n < 4; ++n)
            acc[n] = __builtin_amdgcn_mfma_f32_16x16x32_bf16(a, wr[n][ks], acc[n], 0, 0, 0);
    }
#pragma unroll
    for (int n = 0; n < 4; ++n) {
        int colg = (ntg0 + n) * 16 + (lane & 15);
#pragma unroll
        for (int q = 0; q < 4; ++q) {
            int rid = rid0 + m * 16 + (lane >> 4) * 4 + q;
            int bb = rid >> 9, tt = rid & 511;
            float th = tanhfast(acc[n][q]);
            enc[(size_t)(tt * BATCH + bb) * DFEAT + colg] = (__bf16)th;
        }
    }
}

// ---------------------------------------------------------------------------
// Persistent LSTM, 16 groups x 16 wgs (r6 geometry), r6-proven LLC protocol.
// Round-7 changes are SCHEDULING only:
//  - all per-step address math hoisted to loop-invariant pointers
//  - all-wave relaxed poll (no post-poll barrier; plain sc1 loads, no inv)
//  - per-wave flag publish: inline s_waitcnt vmcnt(0) after own h stores,
//    then lane0 stores flag[wg*16+wave] (readers poll 4 flags/wg = 64/group)
//  - enc staging for t+1 via global_load_lds issued at step tail; its wait
//    is folded into the tail __syncthreads (drains vmcnt) -> 3 barriers/step
// ---------------------------------------------------------------------------
__global__ __launch_bounds__(256, 1) void lstm_kernel(const __bf16* __restrict__ enc,
                                                      const __bf16* __restrict__ wcat,
                                                      const float* __restrict__ blstm,
                                                      __bf16* __restrict__ hbuf,
                                                      unsigned int* __restrict__ flags) {
    extern __shared__ char smem[];
    __bf16* afrag = reinterpret_cast<__bf16*>(smem);       // 24576 B: 1536 chunks
    float* zbuf = reinterpret_cast<float*>(smem + 24576);  // 8192 B: [4][16][32]

    const int tid = threadIdx.x;
    const int lane = tid & 63, np = tid >> 6;   // np = wave = gate
    const int grp = blockIdx.x & 15, widx = blockIdx.x >> 4;
    const int b0 = grp * 16;

    // persistent weight frags: wave np holds gate np, Ntiles nt2 in {0,1}
    bf16x8 wreg[2][24];
#pragma unroll
    for (int nt2 = 0; nt2 < 2; ++nt2)
#pragma unroll
        for (int ks = 0; ks < 24; ++ks)
            wreg[nt2][ks] = *reinterpret_cast<const bf16x8*>(
                wcat + (size_t)((((widx * 8 + np * 2 + nt2) * 24) + ks) * 64 + lane) * 8);
    const float bias0 = blstm[np * 512 + widx * 32 + (lane & 15)];
    const float bias1 = blstm[np * 512 + widx * 32 + 16 + (lane & 15)];

    // ---- hoisted loop-invariant addresses ----
    const int row = tid & 15;                                 // staging row
    const int kq = (tid >> 6) * 32 + ((tid >> 4) & 3) * 8;    // k within 128-quarter
    const __bf16* encp = enc + (size_t)(b0 + row) * DFEAT + kq;   // chunk c0; c1 = +128
    const __bf16* hpA = hbuf + (size_t)(b0 + row) * DLAT + kq;    // parity 0
    const __bf16* hpB = hpA + (size_t)BATCH * DLAT;               // parity 1
    __bf16* enc_lds = afrag + tid * 8;          // chunk tid (byte tid*16); c1 at +2048 elems
    __bf16* h_lds = afrag + (512 + tid) * 8;    // h chunk ii=0; +2048 elems per ii
    const int cell = 2 * tid;
    const int crow = cell >> 5, ccol = cell & 31;
    unsigned* hdA = reinterpret_cast<unsigned*>(
        hbuf + (size_t)(b0 + crow) * DLAT + widx * 32 + ccol);            // parity 0
    unsigned* hdB = reinterpret_cast<unsigned*>(
        hbuf + (size_t)BATCH * DLAT + (size_t)(b0 + crow) * DLAT + widx * 32 + ccol);
    const unsigned* pollp = &flags[(grp * 16 + (lane >> 2)) * 16 + (lane & 3)];
    unsigned* myflag = &flags[(grp * 16 + widx) * 16 + np];
    const float* zg = zbuf + crow * 32 + ccol;                 // + g*512 per gate
    float* zst = zbuf + np * 512 + ((lane >> 4) * 4) * 32 + (lane & 15);
    const __bf16* abase = afrag + lane * 8;                    // + ks*512 per ks

    float c0 = 0.f, c1 = 0.f;

    // prologue: stage enc(0) direct to LDS; tail barrier drains vmcnt
    __builtin_amdgcn_global_load_lds((glb_u32*)encp, (lds_u32*)enc_lds, 16, 0, 0);
    __builtin_amdgcn_global_load_lds((glb_u32*)(encp + 128), (lds_u32*)(enc_lds + 2048), 16, 0, 0);
    encp += (size_t)BATCH * DFEAT;
    __syncthreads();

#pragma unroll 1
    for (int t = 0; t < TLEN; ++t) {
        // (1) enc-part MFMAs (ks 0..7) -- h-independent, overlaps peer lateness
        f32x4 acc0 = (f32x4){bias0, bias0, bias0, bias0};
        f32x4 acc1 = (f32x4){bias1, bias1, bias1, bias1};
#pragma unroll
        for (int ks = 0; ks < 8; ++ks) {
            bf16x8 a = *reinterpret_cast<const bf16x8*>(abase + ks * 512);
            acc0 = __builtin_amdgcn_mfma_f32_16x16x32_bf16(a, wreg[0][ks], acc0, 0, 0, 0);
            acc1 = __builtin_amdgcn_mfma_f32_16x16x32_bf16(a, wreg[1][ks], acc1, 0, 0, 0);
        }

        if (t > 0) {
            // (2) all-wave relaxed poll of the group's 64 per-wave flags
            unsigned v;
            do {
                v = __hip_atomic_load(pollp, __ATOMIC_RELAXED, __HIP_MEMORY_SCOPE_AGENT);
            } while (!__all((int)(v >= (unsigned)t)));

            // (3) h(t) slice: 4x16B sc1 loads off one base (+imm offsets), stage to LDS
            const __bf16* hp = (t & 1) ? hpB : hpA;
            uint4 d0, d1, d2, d3;
            asm volatile(
                "global_load_dwordx4 %0, %4, off sc1\n\t"
                "global_load_dwordx4 %1, %4, off offset:256 sc1\n\t"
                "global_load_dwordx4 %2, %4, off offset:512 sc1\n\t"
                "global_load_dwordx4 %3, %4, off offset:768 sc1\n\t"
                "s_waitcnt vmcnt(0)"
                : "=&v"(d0), "=&v"(d1), "=&v"(d2), "=&v"(d3)
                : "v"(hp) : "memory");
            *reinterpret_cast<uint4*>(h_lds) = d0;
            *reinterpret_cast<uint4*>(h_lds + 2048) = d1;
            *reinterpret_cast<uint4*>(h_lds + 4096) = d2;
            *reinterpret_cast<uint4*>(h_lds + 6144) = d3;
            __syncthreads();   // b2: h frags visible block-wide

            // (4) h-part MFMAs (ks 8..23)
#pragma unroll
            for (int ks = 8; ks < 24; ++ks) {
                bf16x8 a = *reinterpret_cast<const bf16x8*>(abase + ks * 512);
                acc0 = __builtin_amdgcn_mfma_f32_16x16x32_bf16(a, wreg[0][ks], acc0, 0, 0, 0);
                acc1 = __builtin_amdgcn_mfma_f32_16x16x32_bf16(a, wreg[1][ks], acc1, 0, 0, 0);
            }
        }

        // (5) z exchange via LDS
#pragma unroll
        for (int q = 0; q < 4; ++q) {
            zst[q * 32] = acc0[q];
            zst[q * 32 + 16] = acc1[q];
        }
        __syncthreads();   // b3

        // (6) gates + state update (2 adjacent cells per thread) + h store
        float2 zi = *reinterpret_cast<const float2*>(zg);
        float2 zf = *reinterpret_cast<const float2*>(zg + 512);
        float2 zgt = *reinterpret_cast<const float2*>(zg + 1024);
        float2 zo = *reinterpret_cast<const float2*>(zg + 1536);
        float i0 = sigf(zi.x), f0 = sigf(zf.x), g0 = tanhfast(zgt.x), o0 = sigf(zo.x);
        c0 = f0 * c0 + i0 * g0;
        float h0 = o0 * tanhfast(c0);
        float i1 = sigf(zi.y), f1 = sigf(zf.y), g1 = tanhfast(zgt.y), o1 = sigf(zo.y);
        c1 = f1 * c1 + i1 * g1;
        float h1 = o1 * tanhfast(c1);

        unsigned hpk = (unsigned)bfb(h0) | ((unsigned)bfb(h1) << 16);
        __hip_atomic_store(((t & 1) ? hdA : hdB), hpk, __ATOMIC_RELAXED,
                           __HIP_MEMORY_SCOPE_AGENT);

        // (7) per-wave release: drain own stores, publish own flag
        asm volatile("s_waitcnt vmcnt(0)" ::: "memory");
        if (lane == 0)
            __hip_atomic_store(myflag, (unsigned)(t + 1), __ATOMIC_RELAXED,
                               __HIP_MEMORY_SCOPE_AGENT);

        // (8) prefetch enc(t+1) direct to LDS (after flag: never delays release);
        //     tail barrier drains vmcnt -> frags ready for next iter's step (1)
        if (t + 1 < TLEN) {
            __builtin_amdgcn_global_load_lds((glb_u32*)encp, (lds_u32*)enc_lds, 16, 0, 0);
            __builtin_amdgcn_global_load_lds((glb_u32*)(encp + 128),
                                             (lds_u32*)(enc_lds + 2048), 16, 0, 0);
            encp += (size_t)BATCH * DFEAT;
        }
        __syncthreads();   // b4
    }
}

// ---------------------------------------------------------------------------
// Decoder: out[b] = h_last[b,:] @ W_dec + b_dec. h_last is hbuf[0] (T even).
// ---------------------------------------------------------------------------
__global__ __launch_bounds__(64) void dec_kernel(const __bf16* __restrict__ hbuf,
                                                 const float* __restrict__ wdec,
                                                 const float* __restrict__ bdec,
                                                 float* __restrict__ out) {
    int b = blockIdx.x, lane = threadIdx.x;
    uint4 d = *reinterpret_cast<const uint4*>(hbuf + (size_t)b * DLAT + lane * 8);
    const __bf16* hv = reinterpret_cast<const __bf16*>(&d);
    float4 w0 = *reinterpret_cast<const float4*>(wdec + lane * 8);
    float4 w1 = *reinterpret_cast<const float4*>(wdec + lane * 8 + 4);
    float s = (float)hv[0] * w0.x + (float)hv[1] * w0.y + (float)hv[2] * w0.z +
              (float)hv[3] * w0.w + (float)hv[4] * w1.x + (float)hv[5] * w1.y +
              (float)hv[6] * w1.z + (float)hv[7] * w1.w;
#pragma unroll
    for (int off = 32; off; off >>= 1) s += __shfl_xor(s, off);
    if (lane == 0) out[b] = s + bdec[0];
}

extern "C" void kernel_launch(void* const* d_in, const int* in_sizes, int n_in,
                              void* d_out, int out_size, void* d_ws, size_t ws_size,
                              hipStream_t stream) {
    (void)in_sizes; (void)n_in; (void)out_size; (void)ws_size;
    const float* x     = (const float*)d_in[0];
    const float* Wenc  = (const float*)d_in[1];
    const float* benc  = (const float*)d_in[2];
    const float* Wx    = (const float*)d_in[3];
    const float* Wh    = (const float*)d_in[4];
    const float* blstm = (const float*)d_in[5];
    const float* Wdec  = (const float*)d_in[6];
    const float* bdec  = (const float*)d_in[7];

    char* ws = (char*)d_ws;
    __bf16* wcat  = (__bf16*)(ws + WCAT_OFF);
    __bf16* wencf = (__bf16*)(ws + WENC_OFF);
    __bf16* enc   = (__bf16*)(ws + ENC_OFF);
    __bf16* hbuf  = (__bf16*)(ws + H_OFF);
    unsigned int* flags = (unsigned int*)(ws + FLAG_OFF);

    // zero the per-wave flags each call (deterministic across graph replays)
    (void)hipMemsetAsync(ws + FLAG_OFF, 0, 16384, stream);

    wprep_kernel<<<784, 256, 0, stream>>>(Wx, Wh, Wenc, wcat, wencf);
    enc_kernel<<<dim3(2048, 4), 256, 0, stream>>>(x, benc, wencf, enc);

    // 90 KB dynamic LDS forces 1 block/CU (256 blocks on 256 CUs).
    (void)hipFuncSetAttribute(reinterpret_cast<const void*>(lstm_kernel),
                              hipFuncAttributeMaxDynamicSharedMemorySize, 90112);
    lstm_kernel<<<256, 256, 90112, stream>>>(enc, wcat, blstm, hbuf, flags);

    dec_kernel<<<256, 64, 0, stream>>>(hbuf, Wdec, bdec, (float*)d_out);
}